// Round 8
// baseline (151.274 us; speedup 1.0000x reference)
//
#include <hip/hip_runtime.h>

#define N_PIX 4096
#define HW 64
#define NT 1024
#define T64INF (~0ull)
#define K2TAG 0x51170000u

__device__ __forceinline__ unsigned fmap_desc(float f) {
    unsigned u = __float_as_uint(f);
    unsigned m = u ^ (((unsigned)((int)u >> 31)) | 0x80000000u); // ascending map
    return ~m;                                                   // descending: smaller key = larger value
}
__device__ __forceinline__ float funmap_desc(unsigned k) {
    unsigned m = ~k;
    unsigned u = (m & 0x80000000u) ? (m ^ 0x80000000u) : ~m;
    return __uint_as_float(u);
}

// Lock-free triplet merge. Node ids = pixel ids; total order lev(p) =
// (KEY[p]<<12)|p, smaller lev = elder (higher value, tie -> smaller idx).
// T[x] = (KEY[s]<<24)|(s<<12)|v: comp born at x merges at saddle s into v's
// chain (lev[v] < lev[x]). T64INF = alive. Links strictly lev-decreasing =>
// acyclic; a slot's saddle lev only decreases (CAS-guarded) => no ABA.
__device__ __forceinline__ int tm_rep(unsigned long long* T, int u,
                                      unsigned long long wlev) {
    while (true) {
        unsigned long long t = *(volatile unsigned long long*)&T[u];
        if (t == T64INF) break;
        unsigned long long slev = ((t >> 24) << 12) | ((t >> 12) & 0xFFFull);
        if (slev > wlev) break;
        u = (int)(t & 0xFFFull);
    }
    return u;
}
__device__ void tm_merge(unsigned long long* T, const unsigned* KEY,
                         int a, int b, unsigned long long wlev) {
    for (int guard = 0; guard < (1 << 20); ++guard) {
        int ra = tm_rep(T, a, wlev);
        int rb = tm_rep(T, b, wlev);
        if (ra == rb) return;
        unsigned long long la = ((unsigned long long)KEY[ra] << 12) | (unsigned)ra;
        unsigned long long lb = ((unsigned long long)KEY[rb] << 12) | (unsigned)rb;
        if (la < lb) { int t = ra; ra = rb; rb = t; }   // ra = younger (larger lev)
        unsigned long long old = *(volatile unsigned long long*)&T[ra];
        if (old != T64INF) {
            unsigned long long oslev = ((old >> 24) << 12) | ((old >> 12) & 0xFFFull);
            if (oslev <= wlev) continue;                // stale rep; re-walk
        }
        unsigned long long nv = ((wlev >> 12) << 24) |
                                ((wlev & 0xFFFull) << 12) | (unsigned long long)rb;
        if (atomicCAS(&T[ra], old, nv) != old) continue;
        if (old == T64INF) return;
        // displaced link re-hangs off rb's chain at its original saddle
        a = rb;
        b = (int)(old & 0xFFFull);
        wlev = ((old >> 24) << 12) | ((old >> 12) & 0xFFFull);
    }
}

extern "C" __global__ void __launch_bounds__(NT)
betti_fused_kernel(const float* __restrict__ logits,
                   const float* __restrict__ target,
                   float* __restrict__ out, unsigned* __restrict__ wsK) {
    __shared__ unsigned s_KEY[N_PIX];             // 16KB value keys (desc order)
    __shared__ unsigned long long s_T[N_PIX];     // 32KB triplet slots
    __shared__ unsigned long long s_BK[2048];     // 16KB bar selection keys
    __shared__ unsigned s_BAR[2048];              // 8KB  (x<<12)|saddle
    __shared__ unsigned s_HIST[256];              // 1KB  select histogram
    __shared__ unsigned long long s_lred[16];
    __shared__ float s_fred[16];
    __shared__ unsigned long long s_maxlev, s_pref, s_theta;
    __shared__ int s_cnt, s_done, s_rem, s_m, s_bin, s_bcnt, s_K2;

    const int d = blockIdx.x;        // 0..3 pred sample, 4..7 target sample
    const int smp = d & 3;
    const bool pred = d < 4;
    const int tid = threadIdx.x;
    const int lane = tid & 63, wid = tid >> 6;

    // ---- P0: value keys + slot init ----
    if (pred) {
        for (int p = tid; p < N_PIX; p += NT) {
            float l0 = logits[smp * 2 * N_PIX + p];
            float l1 = logits[smp * 2 * N_PIX + N_PIX + p];
            float mx = fmaxf(l0, l1);
            float e0 = expf(l0 - mx), e1 = expf(l1 - mx);
            float v = e1 / (e0 + e1);
            s_KEY[p] = fmap_desc(v);
            s_T[p] = T64INF;
        }
    } else {
        const float* tg = target + smp * N_PIX;
        const unsigned k1 = fmap_desc(1.0f), k0 = fmap_desc(0.0f);
        for (int p = tid; p < N_PIX; p += NT) {
            s_KEY[p] = (tg[p] > 0.5f) ? k1 : k0;
            s_T[p] = T64INF;
        }
    }
    if (tid == 0) s_cnt = 0;
    __syncthreads();

    // ---- P1: max-lev reduction (global-min-value pixel = essential death) ----
    {
        unsigned long long ml = 0ull;
        for (int p = tid; p < N_PIX; p += NT) {
            unsigned long long lv = ((unsigned long long)s_KEY[p] << 12) | (unsigned)p;
            ml = (lv > ml) ? lv : ml;
        }
        #pragma unroll
        for (int off = 32; off > 0; off >>= 1) {
            unsigned long long o = __shfl_down(ml, off);
            ml = (o > ml) ? o : ml;
        }
        if (lane == 0) s_lred[wid] = ml;
        __syncthreads();
        if (tid == 0) {
            unsigned long long mm = 0ull;
            for (int w = 0; w < 16; ++w) mm = (s_lred[w] > mm) ? s_lred[w] : mm;
            s_maxlev = mm;
        }
        __syncthreads();
    }

    // ---- P2: lock-free triplet merge over all 8064 adjacencies ----
    for (int p = tid; p < N_PIX; p += NT) {
        int r = p >> 6, c = p & 63;
        unsigned long long lp = ((unsigned long long)s_KEY[p] << 12) | (unsigned)p;
        if (c < 63) {
            int q = p + 1;
            unsigned long long lq = ((unsigned long long)s_KEY[q] << 12) | (unsigned)q;
            tm_merge(s_T, s_KEY, p, q, (lp > lq) ? lp : lq);
        }
        if (r < 63) {
            int q = p + HW;
            unsigned long long lq = ((unsigned long long)s_KEY[q] << 12) | (unsigned)q;
            tm_merge(s_T, s_KEY, p, q, (lp > lq) ? lp : lq);
        }
    }
    __syncthreads();

    const unsigned maxkey = (unsigned)(s_maxlev >> 12);
    const int maxpix = (int)(s_maxlev & 0xFFFull);

    if (!pred) {
        // ---- TARGET: K2 = #positive bars (essential uniform via maxkey) ----
        int cnt = 0;
        for (int x = tid; x < N_PIX; x += NT) {
            unsigned long long t = s_T[x];
            unsigned dkey = (t == T64INF) ? maxkey : (unsigned)(t >> 24);
            cnt += (s_KEY[x] < dkey) ? 1 : 0;
        }
        for (int off = 32; off > 0; off >>= 1) cnt += __shfl_down(cnt, off);
        if (lane == 0) s_lred[wid] = (unsigned long long)cnt;
        __syncthreads();
        if (tid == 0) {
            int K2 = 0;
            for (int w = 0; w < 16; ++w) K2 += (int)s_lred[w];
            __threadfence();
            atomicExch(&wsK[smp], K2TAG | (unsigned)K2);
        }
        return;
    }

    // ---- PRED P3: collect positive bars + 64-bit selection keys ----
    for (int x = tid; x < N_PIX; x += NT) {
        unsigned long long t = s_T[x];
        int sdp; unsigned dkey;
        if (t == T64INF) { sdp = maxpix; dkey = maxkey; }
        else { sdp = (int)((t >> 12) & 0xFFFull); dkey = (unsigned)(t >> 24); }
        unsigned bkey = s_KEY[x];
        bool isb = bkey < dkey;          // strictly positive persistence
        unsigned rec = 0; unsigned long long bkv = 0;
        if (isb) {
            float pers = funmap_desc(bkey) - funmap_desc(dkey);
            rec = ((unsigned)x << 12) | (unsigned)sdp;
            bkv = ((unsigned long long)(~__float_as_uint(pers)) << 32) |
                  ((unsigned long long)x << 12) | (unsigned long long)sdp;
        }
        unsigned long long mk = __ballot(isb);
        int nb = __popcll(mk);
        int base = 0;
        if (lane == 0 && nb) base = atomicAdd(&s_cnt, nb);
        base = __shfl(base, 0);
        if (isb) {
            int pos = base + __popcll(mk & ((1ull << lane) - 1ull));
            s_BAR[pos] = rec; s_BK[pos] = bkv;
        }
    }
    __syncthreads();
    const int K1 = s_cnt;

    // ---- spin for target count (target blocks co-resident & much faster) ----
    if (tid == 0) {
        unsigned v;
        do { v = atomicAdd(&wsK[smp], 0u);
             __builtin_amdgcn_s_sleep(8);
        } while ((v >> 16) != (K2TAG >> 16));
        s_K2 = (int)(v & 0xFFFFu);
        s_m = min(K1, s_K2);
    }
    __syncthreads();
    const int m = s_m;

    // ---- P4: radix-select m-th smallest selection key -> theta ----
    unsigned long long theta = 0ull;
    if (m > 0) {
        if (tid == 0) { s_pref = 0ull; s_rem = m - 1; s_done = 0; }
        __syncthreads();
        for (int by = 7; by >= 0; --by) {
            if (s_done) break;                   // uniform post-barrier read
            if (tid < 256) s_HIST[tid] = 0;
            __syncthreads();
            unsigned long long pref = s_pref; int rem = s_rem;
            unsigned long long mhi = (by == 7) ? 0ull : (~0ull << ((by + 1) * 8));
            for (int e = tid; e < K1; e += NT) {
                unsigned long long k = s_BK[e];
                if ((k & mhi) == pref)
                    atomicAdd(&s_HIST[(unsigned)((k >> (by * 8)) & 255ull)], 1u);
            }
            __syncthreads();
            if (tid < 64) {
                unsigned h0 = s_HIST[4 * tid], h1 = s_HIST[4 * tid + 1];
                unsigned h2 = s_HIST[4 * tid + 2], h3 = s_HIST[4 * tid + 3];
                int lsx = (int)(h0 + h1 + h2 + h3);
                int xx = lsx;
                #pragma unroll
                for (int off = 1; off < 64; off <<= 1) { int t2 = __shfl_up(xx, off); if (tid >= off) xx += t2; }
                int excl = xx - lsx;
                if (rem >= excl && rem < excl + lsx) {
                    int rr = rem - excl; int b;
                    if (rr < (int)h0) b = 4 * tid;
                    else if (rr < (int)(h0 + h1)) { b = 4 * tid + 1; rr -= (int)h0; }
                    else if (rr < (int)(h0 + h1 + h2)) { b = 4 * tid + 2; rr -= (int)(h0 + h1); }
                    else { b = 4 * tid + 3; rr -= (int)(h0 + h1 + h2); }
                    s_bin = b; s_rem = rr; s_bcnt = (int)s_HIST[b];
                }
            }
            __syncthreads();
            unsigned long long npref = pref | ((unsigned long long)(unsigned)s_bin << (by * 8));
            if (tid == 0) s_pref = npref;
            if (s_bcnt == 1) {
                unsigned long long mcur = mhi | (0xFFull << (by * 8));
                for (int e = tid; e < K1; e += NT) {
                    unsigned long long k = s_BK[e];
                    if ((k & mcur) == npref) s_theta = k;   // unique writer
                }
                if (tid == 0) s_done = 1;
            }
            __syncthreads();
        }
        theta = s_theta;    // keys unique => early-exit guaranteed
    }

    // ---- P5: loss (matched vs target bar (1,0); unmatched -> diagonal) ----
    float acc = 0.0f;
    for (int e = tid; e < K1; e += NT) {
        unsigned rec = s_BAR[e];
        float b = funmap_desc(s_KEY[rec >> 12]);
        float dd = funmap_desc(s_KEY[rec & 0xFFFu]);
        bool mt = (m > 0) && (s_BK[e] <= theta);
        float v1 = (b - 1.0f) * (b - 1.0f) + dd * dd;
        float v0 = 0.5f * (b - dd) * (b - dd);
        acc += mt ? v1 : v0;
    }
    if (tid == 0 && s_K2 > m) acc += 0.5f * (float)(s_K2 - m);
    for (int off = 32; off > 0; off >>= 1) acc += __shfl_down(acc, off);
    if (lane == 0) s_fred[wid] = acc;
    __syncthreads();
    if (tid == 0) {
        float s = 0.0f;
        for (int w = 0; w < 16; ++w) s += s_fred[w];
        atomicAdd(out, 0.25f * s);
    }
}

extern "C" void kernel_launch(void* const* d_in, const int* in_sizes, int n_in,
                              void* d_out, int out_size, void* d_ws, size_t ws_size,
                              hipStream_t stream) {
    const float* logits = (const float*)d_in[0];   // (4,2,64,64) f32
    const float* target = (const float*)d_in[1];   // (4,64,64) f32
    unsigned* wsK = (unsigned*)d_ws;               // 4 tagged K2 slots

    hipMemsetAsync(d_out, 0, sizeof(float), stream);
    hipLaunchKernelGGL(betti_fused_kernel, dim3(8), dim3(NT), 0, stream,
                       logits, target, (float*)d_out, wsK);
}

// Round 9
// 142.710 us; speedup vs baseline: 1.0600x; 1.0600x over previous
//
#include <hip/hip_runtime.h>

#define N_PIX 4096
#define HW 64
#define NT 1024
#define NPK 2048          // peaks form an independent set => <= 2048
#define T64INF (~0ull)
#define K2TAG 0x51170000u
#define POISON 0xAAAAAAAAu

__device__ __forceinline__ unsigned fmap_desc(float f) {
    unsigned u = __float_as_uint(f);
    unsigned m = u ^ (((unsigned)((int)u >> 31)) | 0x80000000u); // ascending map
    return ~m;                                                   // descending: smaller key = larger value
}
__device__ __forceinline__ float funmap_desc(unsigned k) {
    unsigned m = ~k;
    unsigned u = (m & 0x80000000u) ? (m ^ 0x80000000u) : ~m;
    return __uint_as_float(u);
}

// Lock-free triplet merge in PEAK-RANK space (rank 0 = eldest peak).
// T[r] = (wlev<<12) | v : peak r's component dies at saddle-lev wlev, linking
// into v's chain (v < r). T64INF = alive (INF>>12 > any 44-bit lev).
// Elder compare = integer rank compare (no LDS loads). Links strictly
// rank-decreasing => acyclic; a slot's saddle lev only decreases (CAS-guarded).
__device__ void tm_merge(unsigned long long* T, int a, int b,
                         unsigned long long w) {
    for (int guard = 0; guard < (1 << 20); ++guard) {
        int ra = a;
        while (true) {
            unsigned long long t = *(volatile unsigned long long*)&T[ra];
            if ((t >> 12) > w) break;
            ra = (int)(t & 0xFFFull);
        }
        int rb = b;
        while (true) {
            unsigned long long t = *(volatile unsigned long long*)&T[rb];
            if ((t >> 12) > w) break;
            rb = (int)(t & 0xFFFull);
        }
        if (ra == rb) return;
        if (ra < rb) { int tt = ra; ra = rb; rb = tt; }   // ra = younger (bigger rank)
        unsigned long long old = *(volatile unsigned long long*)&T[ra];
        if ((old >> 12) <= w) continue;                   // stale rep; re-walk
        if (atomicCAS(&T[ra], old, (w << 12) | (unsigned long long)rb) != old)
            continue;                                     // lost race
        if (old == T64INF) return;
        // displaced link re-hangs off rb's chain at its original saddle
        a = rb; b = (int)(old & 0xFFFull); w = old >> 12;
    }
}

extern "C" __global__ void __launch_bounds__(NT)
betti_fused_kernel(const float* __restrict__ logits,
                   const float* __restrict__ target,
                   float* __restrict__ out, unsigned* __restrict__ wsK) {
    __shared__ unsigned s_KEY[N_PIX];             // 16KB value keys
    __shared__ unsigned short s_LBL[N_PIX];       // 8KB  pixel -> basin peak pixel
    __shared__ unsigned short s_PRK[N_PIX];       // 8KB  peak pixel -> rank
    __shared__ unsigned short s_PLIST[NPK];       // 4KB  collected peak pixels
    __shared__ unsigned short s_PPIX[NPK];        // 4KB  rank -> peak pixel
    __shared__ unsigned long long s_PLEV[NPK];    // 16KB peak levs (collect order)
    __shared__ unsigned long long s_TP[NPK];      // 16KB triplet slots
    __shared__ unsigned long long s_BK[NPK];      // 16KB bar selection keys
    __shared__ unsigned s_BAR[NPK];               // 8KB  (birthpix<<12)|deathpix
    __shared__ unsigned s_HIST[256];              // 1KB
    __shared__ unsigned long long s_l64[16];
    __shared__ float s_f32[16];
    __shared__ unsigned long long s_maxlev, s_pref, s_theta;
    __shared__ int s_np, s_cnt, s_done, s_rem, s_m, s_bin, s_bcnt, s_K2;

    const int d = blockIdx.x;        // 0..3 pred sample, 4..7 target sample
    const int smp = d & 3;
    const bool pred = d < 4;
    const int tid = threadIdx.x;
    const int lane = tid & 63, wid = tid >> 6;

    // ---- P0: value keys ----
    if (pred) {
        for (int p = tid; p < N_PIX; p += NT) {
            float l0 = logits[smp * 2 * N_PIX + p];
            float l1 = logits[smp * 2 * N_PIX + N_PIX + p];
            float mx = fmaxf(l0, l1);
            float e0 = expf(l0 - mx), e1 = expf(l1 - mx);
            s_KEY[p] = fmap_desc(e1 / (e0 + e1));
        }
    } else {
        const float* tg = target + smp * N_PIX;
        const unsigned k1 = fmap_desc(1.0f), k0 = fmap_desc(0.0f);
        for (int p = tid; p < N_PIX; p += NT) s_KEY[p] = (tg[p] > 0.5f) ? k1 : k0;
    }
    if (tid == 0) { s_np = 0; s_cnt = 0; }
    __syncthreads();

    // ---- P1: max-lev reduction (global-min-value pixel = essential death) ----
    {
        unsigned long long ml = 0ull;
        for (int p = tid; p < N_PIX; p += NT) {
            unsigned long long lv = ((unsigned long long)s_KEY[p] << 12) | (unsigned)p;
            ml = (lv > ml) ? lv : ml;
        }
        #pragma unroll
        for (int off = 32; off > 0; off >>= 1) {
            unsigned long long o = __shfl_down(ml, off);
            ml = (o > ml) ? o : ml;
        }
        if (lane == 0) s_l64[wid] = ml;
        __syncthreads();
        if (tid == 0) {
            unsigned long long mm = 0ull;
            for (int w = 0; w < 16; ++w) mm = (s_l64[w] > mm) ? s_l64[w] : mm;
            s_maxlev = mm;
        }
    }

    // ---- P2: steepest-ascent basin pointers + pointer jumping ----
    for (int p = tid; p < N_PIX; p += NT) {
        int rr = p >> 6, cc = p & 63;
        unsigned long long best = ((unsigned long long)s_KEY[p] << 12) | (unsigned)p;
        int bj = p;
        if (rr > 0)  { int q = p - HW; unsigned long long l = ((unsigned long long)s_KEY[q] << 12) | (unsigned)q; if (l < best) { best = l; bj = q; } }
        if (rr < 63) { int q = p + HW; unsigned long long l = ((unsigned long long)s_KEY[q] << 12) | (unsigned)q; if (l < best) { best = l; bj = q; } }
        if (cc > 0)  { int q = p - 1;  unsigned long long l = ((unsigned long long)s_KEY[q] << 12) | (unsigned)q; if (l < best) { best = l; bj = q; } }
        if (cc < 63) { int q = p + 1;  unsigned long long l = ((unsigned long long)s_KEY[q] << 12) | (unsigned)q; if (l < best) { best = l; bj = q; } }
        s_LBL[p] = (unsigned short)bj;
    }
    __syncthreads();
    for (int it = 0; it < 12; ++it) {   // paths up to 4095 -> 12 doubling rounds
        for (int p = tid; p < N_PIX; p += NT) {
            unsigned short a = s_LBL[p];
            s_LBL[p] = s_LBL[a];        // benign monotone race (rounds 2-5 proven)
        }
        __syncthreads();
    }

    // ---- P3: collect peaks (LBL[p] == p) ----
    for (int p = tid; p < N_PIX; p += NT) {
        bool pk = ((int)s_LBL[p] == p);
        unsigned long long mk = __ballot(pk);
        int nb = __popcll(mk);
        int base = 0;
        if (lane == 0 && nb) base = atomicAdd(&s_np, nb);
        base = __shfl(base, 0);
        if (pk) {
            int pos = base + __popcll(mk & ((1ull << lane) - 1ull));
            s_PLIST[pos] = (unsigned short)p;
            s_PLEV[pos] = ((unsigned long long)s_KEY[p] << 12) | (unsigned)p;
        }
    }
    __syncthreads();
    const int np = s_np;

    // ---- P4: rank peaks by count-smaller (broadcast loop; levs unique) ----
    {
        unsigned long long L0 = (tid < np) ? s_PLEV[tid] : T64INF;
        unsigned long long L1 = (tid + NT < np) ? s_PLEV[tid + NT] : T64INF;
        int c0 = 0, c1 = 0;
        int i = 0;
        for (; i + 4 <= np; i += 4) {
            unsigned long long a0 = s_PLEV[i],     a1 = s_PLEV[i + 1];
            unsigned long long a2 = s_PLEV[i + 2], a3 = s_PLEV[i + 3];
            c0 += (a0 < L0) + (a1 < L0) + (a2 < L0) + (a3 < L0);
            c1 += (a0 < L1) + (a1 < L1) + (a2 < L1) + (a3 < L1);
        }
        for (; i < np; ++i) {
            unsigned long long a0 = s_PLEV[i];
            c0 += (a0 < L0); c1 += (a0 < L1);
        }
        if (tid < np) {
            int px = s_PLIST[tid];
            s_PPIX[c0] = (unsigned short)px; s_PRK[px] = (unsigned short)c0;
        }
        if (tid + NT < np) {
            int px = s_PLIST[tid + NT];
            s_PPIX[c1] = (unsigned short)px; s_PRK[px] = (unsigned short)c1;
        }
    }
    for (int r = tid; r < NPK; r += NT) s_TP[r] = T64INF;
    __syncthreads();

    // ---- P5: cross-basin edges -> rank-space triplet merge ----
    for (int p = tid; p < N_PIX; p += NT) {
        int rr = p >> 6, cc = p & 63;
        int Lp = s_LBL[p];
        unsigned long long lp = ((unsigned long long)s_KEY[p] << 12) | (unsigned)p;
        if (cc < 63) {
            int q = p + 1; int Lq = s_LBL[q];
            if (Lq != Lp) {
                unsigned long long lq = ((unsigned long long)s_KEY[q] << 12) | (unsigned)q;
                tm_merge(s_TP, (int)s_PRK[Lp], (int)s_PRK[Lq], (lp > lq) ? lp : lq);
            }
        }
        if (rr < 63) {
            int q = p + HW; int Lq = s_LBL[q];
            if (Lq != Lp) {
                unsigned long long lq = ((unsigned long long)s_KEY[q] << 12) | (unsigned)q;
                tm_merge(s_TP, (int)s_PRK[Lp], (int)s_PRK[Lq], (lp > lq) ? lp : lq);
            }
        }
    }
    __syncthreads();

    const unsigned maxkey = (unsigned)(s_maxlev >> 12);
    const int maxpix = (int)(s_maxlev & 0xFFFull);

    if (!pred) {
        // ---- TARGET: K2 = #positive bars (r==0 = essential), publish ----
        int cnt = 0;
        for (int r = tid; r < np; r += NT) {
            unsigned long long t = s_TP[r];
            unsigned dkey = (r == 0) ? maxkey : (unsigned)(t >> 24);
            cnt += (s_KEY[s_PPIX[r]] < dkey) ? 1 : 0;
        }
        for (int off = 32; off > 0; off >>= 1) cnt += __shfl_down(cnt, off);
        if (lane == 0) s_l64[wid] = (unsigned long long)cnt;
        __syncthreads();
        if (tid == 0) {
            int K2 = 0;
            for (int w = 0; w < 16; ++w) K2 += (int)s_l64[w];
            __threadfence();
            atomicExch(&wsK[smp], K2TAG | (unsigned)K2);
        }
        return;
    }

    // ---- PRED P6: collect positive bars + selection keys ----
    for (int r = tid; r < np; r += NT) {
        unsigned long long t = s_TP[r];
        unsigned dkey; int dpix;
        if (r == 0) { dkey = maxkey; dpix = maxpix; }
        else { dkey = (unsigned)(t >> 24); dpix = (int)((t >> 12) & 0xFFFull); }
        int bpix = s_PPIX[r];
        unsigned bkey = s_KEY[bpix];
        bool isb = bkey < dkey;          // strictly positive persistence
        unsigned rec = 0; unsigned long long bkv = 0;
        if (isb) {
            float pers = funmap_desc(bkey) - funmap_desc(dkey);
            rec = ((unsigned)bpix << 12) | (unsigned)dpix;
            bkv = ((unsigned long long)(~__float_as_uint(pers)) << 32) |
                  ((unsigned long long)r << 12) | (unsigned long long)dpix;
        }
        unsigned long long mk = __ballot(isb);
        int nb = __popcll(mk);
        int base = 0;
        if (lane == 0 && nb) base = atomicAdd(&s_cnt, nb);
        base = __shfl(base, 0);
        if (isb) {
            int pos = base + __popcll(mk & ((1ull << lane) - 1ull));
            s_BAR[pos] = rec; s_BK[pos] = bkv;
        }
    }
    __syncthreads();
    const int K1 = s_cnt;

    // ---- spin for target count (all 8 blocks co-resident on 256 CUs) ----
    if (tid == 0) {
        unsigned v;
        do { v = atomicAdd(&wsK[smp], 0u);
             __builtin_amdgcn_s_sleep(8);
        } while ((v >> 16) != (K2TAG >> 16));
        s_K2 = (int)(v & 0xFFFFu);
        s_m = min(K1, s_K2);
    }
    __syncthreads();
    const int m = s_m;

    // ---- P7: radix-select m-th smallest selection key -> theta ----
    unsigned long long theta = 0ull;
    if (m > 0) {
        if (tid == 0) { s_pref = 0ull; s_rem = m - 1; s_done = 0; }
        __syncthreads();
        for (int by = 7; by >= 0; --by) {
            if (s_done) break;                   // uniform post-barrier read
            if (tid < 256) s_HIST[tid] = 0;
            __syncthreads();
            unsigned long long pref = s_pref; int rem = s_rem;
            unsigned long long mhi = (by == 7) ? 0ull : (~0ull << ((by + 1) * 8));
            for (int e = tid; e < K1; e += NT) {
                unsigned long long k = s_BK[e];
                if ((k & mhi) == pref)
                    atomicAdd(&s_HIST[(unsigned)((k >> (by * 8)) & 255ull)], 1u);
            }
            __syncthreads();
            if (tid < 64) {
                unsigned h0 = s_HIST[4 * tid], h1 = s_HIST[4 * tid + 1];
                unsigned h2 = s_HIST[4 * tid + 2], h3 = s_HIST[4 * tid + 3];
                int lsx = (int)(h0 + h1 + h2 + h3);
                int xx = lsx;
                #pragma unroll
                for (int off = 1; off < 64; off <<= 1) { int t2 = __shfl_up(xx, off); if (tid >= off) xx += t2; }
                int excl = xx - lsx;
                if (rem >= excl && rem < excl + lsx) {
                    int rr = rem - excl; int b;
                    if (rr < (int)h0) b = 4 * tid;
                    else if (rr < (int)(h0 + h1)) { b = 4 * tid + 1; rr -= (int)h0; }
                    else if (rr < (int)(h0 + h1 + h2)) { b = 4 * tid + 2; rr -= (int)(h0 + h1); }
                    else { b = 4 * tid + 3; rr -= (int)(h0 + h1 + h2); }
                    s_bin = b; s_rem = rr; s_bcnt = (int)s_HIST[b];
                }
            }
            __syncthreads();
            unsigned long long npref = pref | ((unsigned long long)(unsigned)s_bin << (by * 8));
            if (tid == 0) s_pref = npref;
            if (s_bcnt == 1) {
                unsigned long long mcur = mhi | (0xFFull << (by * 8));
                for (int e = tid; e < K1; e += NT) {
                    unsigned long long k = s_BK[e];
                    if ((k & mcur) == npref) s_theta = k;   // unique writer
                }
                if (tid == 0) s_done = 1;
            }
            __syncthreads();
        }
        theta = s_theta;    // keys unique (r in low bits) => early-exit guaranteed
    }

    // ---- P8: loss + cross-block finisher (no separate memset kernel) ----
    float acc = 0.0f;
    for (int e = tid; e < K1; e += NT) {
        unsigned rec = s_BAR[e];
        float b = funmap_desc(s_KEY[rec >> 12]);
        float dd = funmap_desc(s_KEY[rec & 0xFFFu]);
        bool mt = (m > 0) && (s_BK[e] <= theta);
        float v1 = (b - 1.0f) * (b - 1.0f) + dd * dd;   // matched vs target (1,0)
        float v0 = 0.5f * (b - dd) * (b - dd);          // unmatched -> diagonal
        acc += mt ? v1 : v0;
    }
    if (tid == 0 && s_K2 > m) acc += 0.5f * (float)(s_K2 - m);  // unmatched (1,0)
    for (int off = 32; off > 0; off >>= 1) acc += __shfl_down(acc, off);
    if (lane == 0) s_f32[wid] = acc;
    __syncthreads();
    if (tid == 0) {
        float ls = 0.0f;
        for (int w = 0; w < 16; ++w) ls += s_f32[w];
        if (smp != 0) {
            // losses >= 0 => sign bit 0 => bits never equal POISON (sign bit 1)
            atomicExch(&wsK[4 + smp], __float_as_uint(ls));
        } else {
            float tot = ls;
            for (int j = 1; j < 4; ++j) {
                unsigned v;
                do { v = atomicAdd(&wsK[4 + j], 0u);
                     __builtin_amdgcn_s_sleep(8);
                } while (v == POISON);
                tot += __uint_as_float(v);
            }
            out[0] = 0.25f * tot;   // unconditional overwrite (out is poisoned)
        }
    }
}

extern "C" void kernel_launch(void* const* d_in, const int* in_sizes, int n_in,
                              void* d_out, int out_size, void* d_ws, size_t ws_size,
                              hipStream_t stream) {
    const float* logits = (const float*)d_in[0];   // (4,2,64,64) f32
    const float* target = (const float*)d_in[1];   // (4,64,64) f32
    unsigned* wsK = (unsigned*)d_ws;               // [0..3] K2 tags, [4..7] loss bits

    hipLaunchKernelGGL(betti_fused_kernel, dim3(8), dim3(NT), 0, stream,
                       logits, target, (float*)d_out, wsK);
}

// Round 10
// 128.016 us; speedup vs baseline: 1.1817x; 1.1148x over previous
//
#include <hip/hip_runtime.h>

#define N_PIX 4096
#define HW 64
#define NT 1024
#define NPK 2048          // peaks form an independent set => <= 2048
#define T64INF (~0ull)
#define K2TAG 0x51170000u
#define POISON 0xAAAAAAAAu

__device__ __forceinline__ unsigned fmap_desc(float f) {
    unsigned u = __float_as_uint(f);
    unsigned m = u ^ (((unsigned)((int)u >> 31)) | 0x80000000u); // ascending map
    return ~m;                                                   // descending: smaller key = larger value
}
__device__ __forceinline__ float funmap_desc(unsigned k) {
    unsigned m = ~k;
    unsigned u = (m & 0x80000000u) ? (m ^ 0x80000000u) : ~m;
    return __uint_as_float(u);
}

// Lock-free triplet merge in PEAK-RANK space (rank 0 = eldest peak).
// T[r] = (wlev<<12) | v : peak r's component dies at saddle-lev wlev, linking
// into v's chain (v < r). T64INF = alive (INF>>12 > any 44-bit lev).
// Elder compare = integer rank compare (no LDS loads). Links strictly
// rank-decreasing => acyclic; a slot's saddle lev only decreases (CAS-guarded).
__device__ void tm_merge(unsigned long long* T, int a, int b,
                         unsigned long long w) {
    for (int guard = 0; guard < (1 << 20); ++guard) {
        int ra = a;
        while (true) {
            unsigned long long t = *(volatile unsigned long long*)&T[ra];
            if ((t >> 12) > w) break;
            ra = (int)(t & 0xFFFull);
        }
        int rb = b;
        while (true) {
            unsigned long long t = *(volatile unsigned long long*)&T[rb];
            if ((t >> 12) > w) break;
            rb = (int)(t & 0xFFFull);
        }
        if (ra == rb) return;
        if (ra < rb) { int tt = ra; ra = rb; rb = tt; }   // ra = younger (bigger rank)
        unsigned long long old = *(volatile unsigned long long*)&T[ra];
        if ((old >> 12) <= w) continue;                   // stale rep; re-walk
        if (atomicCAS(&T[ra], old, (w << 12) | (unsigned long long)rb) != old)
            continue;                                     // lost race
        if (old == T64INF) return;
        // displaced link re-hangs off rb's chain at its original saddle
        a = rb; b = (int)(old & 0xFFFull); w = old >> 12;
    }
}

extern "C" __global__ void __launch_bounds__(NT)
betti_fused_kernel(const float* __restrict__ logits,
                   const float* __restrict__ target,
                   float* __restrict__ out, unsigned* __restrict__ wsK) {
    __shared__ unsigned s_KEY[N_PIX];             // 16KB value keys
    __shared__ unsigned short s_LBL[N_PIX];       // 8KB  pixel -> basin peak pixel
    __shared__ unsigned short s_PRK[N_PIX];       // 8KB  peak pixel -> rank
    __shared__ unsigned short s_PPIX[NPK];        // 4KB  rank -> peak pixel
    __shared__ unsigned long long s_PLEV[NPK];    // 16KB peak levs (sorted in P4)
    __shared__ unsigned long long s_TP[NPK];      // 16KB triplet slots
    __shared__ unsigned long long s_BK[NPK];      // 16KB bar selection keys
    __shared__ unsigned s_BAR[NPK];               // 8KB  (birthpix<<12)|deathpix
    __shared__ unsigned s_HIST[256];              // 1KB
    __shared__ unsigned long long s_l64[16];
    __shared__ float s_f32[16];
    __shared__ unsigned long long s_maxlev, s_pref, s_theta;
    __shared__ int s_np, s_cnt, s_done, s_rem, s_m, s_bin, s_bcnt, s_K2, s_any;

    const int d = blockIdx.x;        // 0..3 pred sample, 4..7 target sample
    const int smp = d & 3;
    const bool pred = d < 4;
    const int tid = threadIdx.x;
    const int lane = tid & 63, wid = tid >> 6;

    // ---- P0: value keys ----
    if (pred) {
        for (int p = tid; p < N_PIX; p += NT) {
            float l0 = logits[smp * 2 * N_PIX + p];
            float l1 = logits[smp * 2 * N_PIX + N_PIX + p];
            float mx = fmaxf(l0, l1);
            float e0 = expf(l0 - mx), e1 = expf(l1 - mx);
            s_KEY[p] = fmap_desc(e1 / (e0 + e1));
        }
    } else {
        const float* tg = target + smp * N_PIX;
        const unsigned k1 = fmap_desc(1.0f), k0 = fmap_desc(0.0f);
        for (int p = tid; p < N_PIX; p += NT) s_KEY[p] = (tg[p] > 0.5f) ? k1 : k0;
    }
    if (tid == 0) { s_np = 0; s_cnt = 0; }
    __syncthreads();

    // ---- P1: max-lev reduction (global-min-value pixel = essential death) ----
    {
        unsigned long long ml = 0ull;
        for (int p = tid; p < N_PIX; p += NT) {
            unsigned long long lv = ((unsigned long long)s_KEY[p] << 12) | (unsigned)p;
            ml = (lv > ml) ? lv : ml;
        }
        #pragma unroll
        for (int off = 32; off > 0; off >>= 1) {
            unsigned long long o = __shfl_down(ml, off);
            ml = (o > ml) ? o : ml;
        }
        if (lane == 0) s_l64[wid] = ml;
        __syncthreads();
        if (tid == 0) {
            unsigned long long mm = 0ull;
            for (int w = 0; w < 16; ++w) mm = (s_l64[w] > mm) ? s_l64[w] : mm;
            s_maxlev = mm;
        }
    }

    // ---- P2: steepest-ascent basin pointers + flagged pointer jumping ----
    for (int p = tid; p < N_PIX; p += NT) {
        int rr = p >> 6, cc = p & 63;
        unsigned long long best = ((unsigned long long)s_KEY[p] << 12) | (unsigned)p;
        int bj = p;
        if (rr > 0)  { int q = p - HW; unsigned long long l = ((unsigned long long)s_KEY[q] << 12) | (unsigned)q; if (l < best) { best = l; bj = q; } }
        if (rr < 63) { int q = p + HW; unsigned long long l = ((unsigned long long)s_KEY[q] << 12) | (unsigned)q; if (l < best) { best = l; bj = q; } }
        if (cc > 0)  { int q = p - 1;  unsigned long long l = ((unsigned long long)s_KEY[q] << 12) | (unsigned)q; if (l < best) { best = l; bj = q; } }
        if (cc < 63) { int q = p + 1;  unsigned long long l = ((unsigned long long)s_KEY[q] << 12) | (unsigned)q; if (l < best) { best = l; bj = q; } }
        s_LBL[p] = (unsigned short)bj;
    }
    __syncthreads();
    for (int it = 0; it < 16; ++it) {   // doubling; flag-terminated (typ ~6 rounds)
        if (tid == 0) s_any = 0;
        __syncthreads();
        bool ch = false;
        for (int p = tid; p < N_PIX; p += NT) {
            unsigned short a = s_LBL[p];
            unsigned short b = s_LBL[a];    // benign monotone race
            if (b != a) { s_LBL[p] = b; ch = true; }
        }
        if (ch) s_any = 1;
        __syncthreads();
        int av = s_any;
        __syncthreads();
        if (!av) break;
    }

    // ---- P3: collect peak levs (LBL[p] == p); pixel id rides in low 12 bits ----
    for (int p = tid; p < N_PIX; p += NT) {
        bool pk = ((int)s_LBL[p] == p);
        unsigned long long mk = __ballot(pk);
        int nb = __popcll(mk);
        int base = 0;
        if (lane == 0 && nb) base = atomicAdd(&s_np, nb);
        base = __shfl(base, 0);
        if (pk) {
            int pos = base + __popcll(mk & ((1ull << lane) - 1ull));
            s_PLEV[pos] = ((unsigned long long)s_KEY[p] << 12) | (unsigned)p;
        }
    }
    __syncthreads();
    const int np = s_np;

    // ---- P4: bitonic sort peak levs asc (1 elem/thread; replaces the
    //      LDS-pipe-bound count-smaller: 16 waves x np redundant reads) ----
    {
        int NS = 64; while (NS < np) NS <<= 1;     // pow2 >= np, <= 2048
        for (int t = tid; t < NS; t += NT) if (t >= np) s_PLEV[t] = T64INF;
        __syncthreads();
        for (int k = 2; k <= NS; k <<= 1)
            for (int j = k >> 1; j > 0; j >>= 1) {
                for (int idx = tid; idx < NS; idx += NT) {
                    int ixj = idx ^ j;
                    if (ixj > idx) {
                        unsigned long long a = s_PLEV[idx], b = s_PLEV[ixj];
                        bool up = ((idx & k) == 0);
                        if ((a > b) == up) { s_PLEV[idx] = b; s_PLEV[ixj] = a; }
                    }
                }
                __syncthreads();
            }
        for (int r = tid; r < np; r += NT) {
            int px = (int)(s_PLEV[r] & 0xFFFull);
            s_PPIX[r] = (unsigned short)px;
            s_PRK[px] = (unsigned short)r;
        }
        for (int r = tid; r < NPK; r += NT) s_TP[r] = T64INF;
        __syncthreads();
    }

    // ---- P5: cross-basin edges -> rank-space triplet merge ----
    for (int p = tid; p < N_PIX; p += NT) {
        int rr = p >> 6, cc = p & 63;
        int Lp = s_LBL[p];
        unsigned long long lp = ((unsigned long long)s_KEY[p] << 12) | (unsigned)p;
        if (cc < 63) {
            int q = p + 1; int Lq = s_LBL[q];
            if (Lq != Lp) {
                unsigned long long lq = ((unsigned long long)s_KEY[q] << 12) | (unsigned)q;
                tm_merge(s_TP, (int)s_PRK[Lp], (int)s_PRK[Lq], (lp > lq) ? lp : lq);
            }
        }
        if (rr < 63) {
            int q = p + HW; int Lq = s_LBL[q];
            if (Lq != Lp) {
                unsigned long long lq = ((unsigned long long)s_KEY[q] << 12) | (unsigned)q;
                tm_merge(s_TP, (int)s_PRK[Lp], (int)s_PRK[Lq], (lp > lq) ? lp : lq);
            }
        }
    }
    __syncthreads();

    const unsigned maxkey = (unsigned)(s_maxlev >> 12);
    const int maxpix = (int)(s_maxlev & 0xFFFull);

    if (!pred) {
        // ---- TARGET: K2 = #positive bars (r==0 = essential), publish ----
        int cnt = 0;
        for (int r = tid; r < np; r += NT) {
            unsigned long long t = s_TP[r];
            unsigned dkey = (r == 0) ? maxkey : (unsigned)(t >> 24);
            cnt += (s_KEY[s_PPIX[r]] < dkey) ? 1 : 0;
        }
        for (int off = 32; off > 0; off >>= 1) cnt += __shfl_down(cnt, off);
        if (lane == 0) s_l64[wid] = (unsigned long long)cnt;
        __syncthreads();
        if (tid == 0) {
            int K2 = 0;
            for (int w = 0; w < 16; ++w) K2 += (int)s_l64[w];
            __threadfence();
            atomicExch(&wsK[smp], K2TAG | (unsigned)K2);
        }
        return;
    }

    // ---- PRED P6: collect positive bars + selection keys ----
    for (int r = tid; r < np; r += NT) {
        unsigned long long t = s_TP[r];
        unsigned dkey; int dpix;
        if (r == 0) { dkey = maxkey; dpix = maxpix; }
        else { dkey = (unsigned)(t >> 24); dpix = (int)((t >> 12) & 0xFFFull); }
        int bpix = s_PPIX[r];
        unsigned bkey = s_KEY[bpix];
        bool isb = bkey < dkey;          // strictly positive persistence
        unsigned rec = 0; unsigned long long bkv = 0;
        if (isb) {
            float pers = funmap_desc(bkey) - funmap_desc(dkey);
            rec = ((unsigned)bpix << 12) | (unsigned)dpix;
            bkv = ((unsigned long long)(~__float_as_uint(pers)) << 32) |
                  ((unsigned long long)r << 12) | (unsigned long long)dpix;
        }
        unsigned long long mk = __ballot(isb);
        int nb = __popcll(mk);
        int base = 0;
        if (lane == 0 && nb) base = atomicAdd(&s_cnt, nb);
        base = __shfl(base, 0);
        if (isb) {
            int pos = base + __popcll(mk & ((1ull << lane) - 1ull));
            s_BAR[pos] = rec; s_BK[pos] = bkv;
        }
    }
    __syncthreads();
    const int K1 = s_cnt;

    // ---- spin for target count (all 8 blocks co-resident on 256 CUs) ----
    if (tid == 0) {
        unsigned v;
        do { v = atomicAdd(&wsK[smp], 0u);
             __builtin_amdgcn_s_sleep(8);
        } while ((v >> 16) != (K2TAG >> 16));
        s_K2 = (int)(v & 0xFFFFu);
        s_m = min(K1, s_K2);
    }
    __syncthreads();
    const int m = s_m;

    // ---- P7: radix-select m-th smallest selection key -> theta ----
    unsigned long long theta = 0ull;
    if (m > 0) {
        if (tid == 0) { s_pref = 0ull; s_rem = m - 1; s_done = 0; }
        __syncthreads();
        for (int by = 7; by >= 0; --by) {
            if (s_done) break;                   // uniform post-barrier read
            if (tid < 256) s_HIST[tid] = 0;
            __syncthreads();
            unsigned long long pref = s_pref; int rem = s_rem;
            unsigned long long mhi = (by == 7) ? 0ull : (~0ull << ((by + 1) * 8));
            for (int e = tid; e < K1; e += NT) {
                unsigned long long k = s_BK[e];
                if ((k & mhi) == pref)
                    atomicAdd(&s_HIST[(unsigned)((k >> (by * 8)) & 255ull)], 1u);
            }
            __syncthreads();
            if (tid < 64) {
                unsigned h0 = s_HIST[4 * tid], h1 = s_HIST[4 * tid + 1];
                unsigned h2 = s_HIST[4 * tid + 2], h3 = s_HIST[4 * tid + 3];
                int lsx = (int)(h0 + h1 + h2 + h3);
                int xx = lsx;
                #pragma unroll
                for (int off = 1; off < 64; off <<= 1) { int t2 = __shfl_up(xx, off); if (tid >= off) xx += t2; }
                int excl = xx - lsx;
                if (rem >= excl && rem < excl + lsx) {
                    int rr = rem - excl; int b;
                    if (rr < (int)h0) b = 4 * tid;
                    else if (rr < (int)(h0 + h1)) { b = 4 * tid + 1; rr -= (int)h0; }
                    else if (rr < (int)(h0 + h1 + h2)) { b = 4 * tid + 2; rr -= (int)(h0 + h1); }
                    else { b = 4 * tid + 3; rr -= (int)(h0 + h1 + h2); }
                    s_bin = b; s_rem = rr; s_bcnt = (int)s_HIST[b];
                }
            }
            __syncthreads();
            unsigned long long npref = pref | ((unsigned long long)(unsigned)s_bin << (by * 8));
            if (tid == 0) s_pref = npref;
            if (s_bcnt == 1) {
                unsigned long long mcur = mhi | (0xFFull << (by * 8));
                for (int e = tid; e < K1; e += NT) {
                    unsigned long long k = s_BK[e];
                    if ((k & mcur) == npref) s_theta = k;   // unique writer
                }
                if (tid == 0) s_done = 1;
            }
            __syncthreads();
        }
        theta = s_theta;    // keys unique (r in low bits) => early-exit guaranteed
    }

    // ---- P8: loss + cross-block finisher (no separate memset kernel) ----
    float acc = 0.0f;
    for (int e = tid; e < K1; e += NT) {
        unsigned rec = s_BAR[e];
        float b = funmap_desc(s_KEY[rec >> 12]);
        float dd = funmap_desc(s_KEY[rec & 0xFFFu]);
        bool mt = (m > 0) && (s_BK[e] <= theta);
        float v1 = (b - 1.0f) * (b - 1.0f) + dd * dd;   // matched vs target (1,0)
        float v0 = 0.5f * (b - dd) * (b - dd);          // unmatched -> diagonal
        acc += mt ? v1 : v0;
    }
    if (tid == 0 && s_K2 > m) acc += 0.5f * (float)(s_K2 - m);  // unmatched (1,0)
    for (int off = 32; off > 0; off >>= 1) acc += __shfl_down(acc, off);
    if (lane == 0) s_f32[wid] = acc;
    __syncthreads();
    if (tid == 0) {
        float ls = 0.0f;
        for (int w = 0; w < 16; ++w) ls += s_f32[w];
        if (smp != 0) {
            // losses >= 0 => sign bit 0 => bits never equal POISON (sign bit 1)
            atomicExch(&wsK[4 + smp], __float_as_uint(ls));
        } else {
            float tot = ls;
            for (int j = 1; j < 4; ++j) {
                unsigned v;
                do { v = atomicAdd(&wsK[4 + j], 0u);
                     __builtin_amdgcn_s_sleep(8);
                } while (v == POISON);
                tot += __uint_as_float(v);
            }
            out[0] = 0.25f * tot;   // unconditional overwrite (out is poisoned)
        }
    }
}

extern "C" void kernel_launch(void* const* d_in, const int* in_sizes, int n_in,
                              void* d_out, int out_size, void* d_ws, size_t ws_size,
                              hipStream_t stream) {
    const float* logits = (const float*)d_in[0];   // (4,2,64,64) f32
    const float* target = (const float*)d_in[1];   // (4,64,64) f32
    unsigned* wsK = (unsigned*)d_ws;               // [0..3] K2 tags, [4..7] loss bits

    hipLaunchKernelGGL(betti_fused_kernel, dim3(8), dim3(NT), 0, stream,
                       logits, target, (float*)d_out, wsK);
}

// Round 11
// 112.996 us; speedup vs baseline: 1.3388x; 1.1329x over previous
//
#include <hip/hip_runtime.h>

#define N_PIX 4096
#define HW 64
#define NT 1024
#define NPK 2048          // peaks form an independent set => <= 2048
#define ALIVE_BIT (1ull << 63)
#define LEV44 0xFFFFFFFFFFFull
#define K2TAG 0x51170000u
#define POISON 0xAAAAAAAAu

__device__ __forceinline__ unsigned fmap_desc(float f) {
    unsigned u = __float_as_uint(f);
    unsigned m = u ^ (((unsigned)((int)u >> 31)) | 0x80000000u); // ascending map
    return ~m;                                                   // descending: smaller key = larger value
}
__device__ __forceinline__ float funmap_desc(unsigned k) {
    unsigned m = ~k;
    unsigned u = (m & 0x80000000u) ? (m ^ 0x80000000u) : ~m;
    return __uint_as_float(u);
}

// Lock-free triplet merge; node ids = collect order (arbitrary).
// T[x] alive : ALIVE_BIT | ownlev44   (lev = (KEY<<12)|pix, unique)
// T[x] dead  : (saddlelev44 << 12) | v  (component died, linked into v).
// Walk predicate (t>>12) > w stops at both {alive} and {dead at saddle > w}
// since ALIVE_BIT>>12 dwarfs any 44-bit lev. Elder = smaller lev; the walk's
// final read supplies an alive root's lev free; dead-later reps read LEV[].
// Links strictly lev-decreasing => acyclic; slot saddle only decreases.
__device__ void tm_merge(unsigned long long* T, const unsigned long long* LEV,
                         int a, int b, unsigned long long w) {
    for (int guard = 0; guard < (1 << 20); ++guard) {
        int ra = a; unsigned long long ta;
        while (true) {
            ta = *(volatile unsigned long long*)&T[ra];
            if ((ta >> 12) > w) break;
            ra = (int)(ta & 0xFFFull);
        }
        int rb = b; unsigned long long tb;
        while (true) {
            tb = *(volatile unsigned long long*)&T[rb];
            if ((tb >> 12) > w) break;
            rb = (int)(tb & 0xFFFull);
        }
        if (ra == rb) return;
        unsigned long long la = (ta >> 63) ? (ta & LEV44) : LEV[ra];
        unsigned long long lb = (tb >> 63) ? (tb & LEV44) : LEV[rb];
        if (la < lb) { int tt = ra; ra = rb; rb = tt; }   // ra = younger (bigger lev)
        unsigned long long old = *(volatile unsigned long long*)&T[ra];
        if ((old >> 12) <= w) continue;                   // stale rep; re-walk
        if (atomicCAS(&T[ra], old, (w << 12) | (unsigned long long)rb) != old)
            continue;                                     // lost race
        if (old >> 63) return;                            // was alive: done
        // displaced link re-hangs off rb's chain at its original saddle
        a = rb; b = (int)(old & 0xFFFull); w = old >> 12;
    }
}

extern "C" __global__ void __launch_bounds__(NT)
betti_fused_kernel(const float* __restrict__ logits,
                   const float* __restrict__ target,
                   float* __restrict__ out, unsigned* __restrict__ wsK) {
    __shared__ unsigned s_KEY[N_PIX];             // 16KB value keys
    __shared__ unsigned short s_LBL[N_PIX];       // 8KB  pixel -> basin peak pixel
    __shared__ unsigned short s_NIDX[N_PIX];      // 8KB  peak pixel -> node idx
    __shared__ unsigned long long s_LEV[NPK];     // 16KB node idx -> lev
    __shared__ unsigned long long s_TP[NPK];      // 16KB triplet slots
    __shared__ unsigned long long s_BK[NPK];      // 16KB bar selection keys
    __shared__ unsigned s_BAR[NPK];               // 8KB  (birthpix<<12)|deathpix
    __shared__ unsigned s_HIST[256];              // 1KB
    __shared__ unsigned long long s_l64[16];
    __shared__ float s_f32[16];
    __shared__ int s_anyf[20];
    __shared__ unsigned long long s_maxlev, s_pref, s_theta;
    __shared__ int s_np, s_cnt, s_done, s_rem, s_m, s_bin, s_bcnt, s_K2;

    const int d = blockIdx.x;        // 0..3 pred sample, 4..7 target sample
    const int smp = d & 3;
    const bool pred = d < 4;
    const int tid = threadIdx.x;
    const int lane = tid & 63, wid = tid >> 6;

    // ---- P0: value keys ----
    if (pred) {
        for (int p = tid; p < N_PIX; p += NT) {
            float l0 = logits[smp * 2 * N_PIX + p];
            float l1 = logits[smp * 2 * N_PIX + N_PIX + p];
            float mx = fmaxf(l0, l1);
            float e0 = expf(l0 - mx), e1 = expf(l1 - mx);
            s_KEY[p] = fmap_desc(e1 / (e0 + e1));
        }
    } else {
        const float* tg = target + smp * N_PIX;
        const unsigned k1 = fmap_desc(1.0f), k0 = fmap_desc(0.0f);
        for (int p = tid; p < N_PIX; p += NT) s_KEY[p] = (tg[p] > 0.5f) ? k1 : k0;
    }
    if (tid == 0) { s_np = 0; s_cnt = 0; }
    if (tid < 20) s_anyf[tid] = 0;
    __syncthreads();

    // ---- P1: max-lev reduction (global-min-value pixel = essential death) ----
    {
        unsigned long long ml = 0ull;
        for (int p = tid; p < N_PIX; p += NT) {
            unsigned long long lv = ((unsigned long long)s_KEY[p] << 12) | (unsigned)p;
            ml = (lv > ml) ? lv : ml;
        }
        #pragma unroll
        for (int off = 32; off > 0; off >>= 1) {
            unsigned long long o = __shfl_down(ml, off);
            ml = (o > ml) ? o : ml;
        }
        if (lane == 0) s_l64[wid] = ml;
        __syncthreads();
        if (tid == 0) {
            unsigned long long mm = 0ull;
            for (int w = 0; w < 16; ++w) mm = (s_l64[w] > mm) ? s_l64[w] : mm;
            s_maxlev = mm;
        }
    }

    // ---- P2: steepest-ascent basin pointers + 1-barrier/iter jumping ----
    for (int p = tid; p < N_PIX; p += NT) {
        int rr = p >> 6, cc = p & 63;
        unsigned long long best = ((unsigned long long)s_KEY[p] << 12) | (unsigned)p;
        int bj = p;
        if (rr > 0)  { int q = p - HW; unsigned long long l = ((unsigned long long)s_KEY[q] << 12) | (unsigned)q; if (l < best) { best = l; bj = q; } }
        if (rr < 63) { int q = p + HW; unsigned long long l = ((unsigned long long)s_KEY[q] << 12) | (unsigned)q; if (l < best) { best = l; bj = q; } }
        if (cc > 0)  { int q = p - 1;  unsigned long long l = ((unsigned long long)s_KEY[q] << 12) | (unsigned)q; if (l < best) { best = l; bj = q; } }
        if (cc < 63) { int q = p + 1;  unsigned long long l = ((unsigned long long)s_KEY[q] << 12) | (unsigned)q; if (l < best) { best = l; bj = q; } }
        s_LBL[p] = (unsigned short)bj;
    }
    __syncthreads();
    for (int it = 0; it < 14; ++it) {   // doubling; per-iter flag slot (no reset)
        bool ch = false;
        for (int p = tid; p < N_PIX; p += NT) {
            unsigned short a = s_LBL[p];
            unsigned short b = s_LBL[a];    // benign monotone race
            if (b != a) { s_LBL[p] = b; ch = true; }
        }
        if (ch) s_anyf[it] = 1;
        __syncthreads();
        if (!s_anyf[it]) break;             // uniform post-barrier read
    }

    // ---- P3: collect peaks (LBL[p]==p): node idx = collect order ----
    for (int p = tid; p < N_PIX; p += NT) {
        bool pk = ((int)s_LBL[p] == p);
        unsigned long long mk = __ballot(pk);
        int nb = __popcll(mk);
        int base = 0;
        if (lane == 0 && nb) base = atomicAdd(&s_np, nb);
        base = __shfl(base, 0);
        if (pk) {
            int pos = base + __popcll(mk & ((1ull << lane) - 1ull));
            unsigned long long lv = ((unsigned long long)s_KEY[p] << 12) | (unsigned)p;
            s_LEV[pos] = lv;
            s_TP[pos] = ALIVE_BIT | lv;
            s_NIDX[p] = (unsigned short)pos;
        }
    }
    __syncthreads();
    const int np = s_np;

    // ---- P5: cross-basin edges -> triplet merge (elder = smaller lev) ----
    for (int p = tid; p < N_PIX; p += NT) {
        int rr = p >> 6, cc = p & 63;
        int Lp = s_LBL[p];
        unsigned long long lp = ((unsigned long long)s_KEY[p] << 12) | (unsigned)p;
        if (cc < 63) {
            int q = p + 1; int Lq = s_LBL[q];
            if (Lq != Lp) {
                unsigned long long lq = ((unsigned long long)s_KEY[q] << 12) | (unsigned)q;
                tm_merge(s_TP, s_LEV, (int)s_NIDX[Lp], (int)s_NIDX[Lq], (lp > lq) ? lp : lq);
            }
        }
        if (rr < 63) {
            int q = p + HW; int Lq = s_LBL[q];
            if (Lq != Lp) {
                unsigned long long lq = ((unsigned long long)s_KEY[q] << 12) | (unsigned)q;
                tm_merge(s_TP, s_LEV, (int)s_NIDX[Lp], (int)s_NIDX[Lq], (lp > lq) ? lp : lq);
            }
        }
    }
    __syncthreads();

    const unsigned maxkey = (unsigned)(s_maxlev >> 12);
    const int maxpix = (int)(s_maxlev & 0xFFFull);

    if (!pred) {
        // ---- TARGET: K2 = #positive bars (alive node = essential), publish ----
        int cnt = 0;
        for (int x = tid; x < np; x += NT) {
            unsigned long long t = s_TP[x];
            unsigned dkey = (t >> 63) ? maxkey : (unsigned)(t >> 24);
            unsigned bkey = (unsigned)(s_LEV[x] >> 12);
            cnt += (bkey < dkey) ? 1 : 0;
        }
        for (int off = 32; off > 0; off >>= 1) cnt += __shfl_down(cnt, off);
        if (lane == 0) s_l64[wid] = (unsigned long long)cnt;
        __syncthreads();
        if (tid == 0) {
            int K2 = 0;
            for (int w = 0; w < 16; ++w) K2 += (int)s_l64[w];
            __threadfence();
            atomicExch(&wsK[smp], K2TAG | (unsigned)K2);
        }
        return;
    }

    // ---- PRED P6: collect positive bars + selection keys ----
    for (int x = tid; x < np; x += NT) {
        unsigned long long t = s_TP[x];
        unsigned long long lv = s_LEV[x];
        unsigned dkey; int dpix;
        if (t >> 63) { dkey = maxkey; dpix = maxpix; }
        else { dkey = (unsigned)(t >> 24); dpix = (int)((t >> 12) & 0xFFFull); }
        int bpix = (int)(lv & 0xFFFull);
        unsigned bkey = (unsigned)(lv >> 12);
        bool isb = bkey < dkey;          // strictly positive persistence
        unsigned rec = 0; unsigned long long bkv = 0;
        if (isb) {
            float pers = funmap_desc(bkey) - funmap_desc(dkey);
            rec = ((unsigned)bpix << 12) | (unsigned)dpix;
            bkv = ((unsigned long long)(~__float_as_uint(pers)) << 32) |
                  ((unsigned long long)x << 12) | (unsigned long long)dpix;
        }
        unsigned long long mk = __ballot(isb);
        int nb = __popcll(mk);
        int base = 0;
        if (lane == 0 && nb) base = atomicAdd(&s_cnt, nb);
        base = __shfl(base, 0);
        if (isb) {
            int pos = base + __popcll(mk & ((1ull << lane) - 1ull));
            s_BAR[pos] = rec; s_BK[pos] = bkv;
        }
    }
    __syncthreads();
    const int K1 = s_cnt;

    // ---- spin for target count (all 8 blocks co-resident on 256 CUs) ----
    if (tid == 0) {
        unsigned v;
        do { v = atomicAdd(&wsK[smp], 0u);
             __builtin_amdgcn_s_sleep(8);
        } while ((v >> 16) != (K2TAG >> 16));
        s_K2 = (int)(v & 0xFFFFu);
        s_m = min(K1, s_K2);
    }
    __syncthreads();
    const int m = s_m;

    // ---- P7: radix-select m-th smallest selection key -> theta ----
    unsigned long long theta = 0ull;
    if (m > 0) {
        if (tid == 0) { s_pref = 0ull; s_rem = m - 1; s_done = 0; }
        __syncthreads();
        for (int by = 7; by >= 0; --by) {
            if (s_done) break;                   // uniform post-barrier read
            if (tid < 256) s_HIST[tid] = 0;
            __syncthreads();
            unsigned long long pref = s_pref; int rem = s_rem;
            unsigned long long mhi = (by == 7) ? 0ull : (~0ull << ((by + 1) * 8));
            for (int e = tid; e < K1; e += NT) {
                unsigned long long k = s_BK[e];
                if ((k & mhi) == pref)
                    atomicAdd(&s_HIST[(unsigned)((k >> (by * 8)) & 255ull)], 1u);
            }
            __syncthreads();
            if (tid < 64) {
                unsigned h0 = s_HIST[4 * tid], h1 = s_HIST[4 * tid + 1];
                unsigned h2 = s_HIST[4 * tid + 2], h3 = s_HIST[4 * tid + 3];
                int lsx = (int)(h0 + h1 + h2 + h3);
                int xx = lsx;
                #pragma unroll
                for (int off = 1; off < 64; off <<= 1) { int t2 = __shfl_up(xx, off); if (tid >= off) xx += t2; }
                int excl = xx - lsx;
                if (rem >= excl && rem < excl + lsx) {
                    int rr = rem - excl; int b;
                    if (rr < (int)h0) b = 4 * tid;
                    else if (rr < (int)(h0 + h1)) { b = 4 * tid + 1; rr -= (int)h0; }
                    else if (rr < (int)(h0 + h1 + h2)) { b = 4 * tid + 2; rr -= (int)(h0 + h1); }
                    else { b = 4 * tid + 3; rr -= (int)(h0 + h1 + h2); }
                    s_bin = b; s_rem = rr; s_bcnt = (int)s_HIST[b];
                }
            }
            __syncthreads();
            unsigned long long npref = pref | ((unsigned long long)(unsigned)s_bin << (by * 8));
            if (tid == 0) s_pref = npref;
            if (s_bcnt == 1) {
                unsigned long long mcur = mhi | (0xFFull << (by * 8));
                for (int e = tid; e < K1; e += NT) {
                    unsigned long long k = s_BK[e];
                    if ((k & mcur) == npref) s_theta = k;   // unique writer
                }
                if (tid == 0) s_done = 1;
            }
            __syncthreads();
        }
        theta = s_theta;    // keys unique (node idx in low bits) => exit guaranteed
    }

    // ---- P8: loss + cross-block finisher (no separate memset kernel) ----
    float acc = 0.0f;
    for (int e = tid; e < K1; e += NT) {
        unsigned rec = s_BAR[e];
        float b = funmap_desc(s_KEY[rec >> 12]);
        float dd = funmap_desc(s_KEY[rec & 0xFFFu]);
        bool mt = (m > 0) && (s_BK[e] <= theta);
        float v1 = (b - 1.0f) * (b - 1.0f) + dd * dd;   // matched vs target (1,0)
        float v0 = 0.5f * (b - dd) * (b - dd);          // unmatched -> diagonal
        acc += mt ? v1 : v0;
    }
    if (tid == 0 && s_K2 > m) acc += 0.5f * (float)(s_K2 - m);  // unmatched (1,0)
    for (int off = 32; off > 0; off >>= 1) acc += __shfl_down(acc, off);
    if (lane == 0) s_f32[wid] = acc;
    __syncthreads();
    if (tid == 0) {
        float ls = 0.0f;
        for (int w = 0; w < 16; ++w) ls += s_f32[w];
        if (smp != 0) {
            // losses >= 0 => sign bit 0 => bits never equal POISON (sign bit 1)
            atomicExch(&wsK[4 + smp], __float_as_uint(ls));
        } else {
            float tot = ls;
            for (int j = 1; j < 4; ++j) {
                unsigned v;
                do { v = atomicAdd(&wsK[4 + j], 0u);
                     __builtin_amdgcn_s_sleep(8);
                } while (v == POISON);
                tot += __uint_as_float(v);
            }
            out[0] = 0.25f * tot;   // unconditional overwrite (out is poisoned)
        }
    }
}

extern "C" void kernel_launch(void* const* d_in, const int* in_sizes, int n_in,
                              void* d_out, int out_size, void* d_ws, size_t ws_size,
                              hipStream_t stream) {
    const float* logits = (const float*)d_in[0];   // (4,2,64,64) f32
    const float* target = (const float*)d_in[1];   // (4,64,64) f32
    unsigned* wsK = (unsigned*)d_ws;               // [0..3] K2 tags, [4..7] loss bits

    hipLaunchKernelGGL(betti_fused_kernel, dim3(8), dim3(NT), 0, stream,
                       logits, target, (float*)d_out, wsK);
}